// Round 1
// baseline (809.518 us; speedup 1.0000x reference)
//
#include <hip/hip_runtime.h>
#include <hip/hip_bf16.h>
#include <math.h>

#define B_ 4
#define C_ 512
#define N_ 4096

typedef float f32x4 __attribute__((ext_vector_type(4)));
typedef __bf16 bf16x8 __attribute__((ext_vector_type(8)));

__device__ __forceinline__ unsigned short f2bf(float x){
    unsigned u = __builtin_bit_cast(unsigned, x);
    return (unsigned short)((u + 0x7FFFu + ((u>>16)&1u)) >> 16);
}
__device__ __forceinline__ float bf2f(unsigned short b){
    unsigned u = ((unsigned)b)<<16;
    return __builtin_bit_cast(float, u);
}
__device__ __forceinline__ f32x4 mfma16(bf16x8 a, bf16x8 b, f32x4 c){
    return __builtin_amdgcn_mfma_f32_16x16x32_bf16(a, b, c, 0, 0, 0);
}

// ---------------- weight fp32 -> bf16 hi/lo split ----------------
__global__ void split_w(const float* __restrict__ src, unsigned short* __restrict__ hi,
                        unsigned short* __restrict__ lo){
    const int i = (blockIdx.x*256 + threadIdx.x)*4;
    f32x4 v = *(const f32x4*)(src + i);
    ushort4 h, l;
    unsigned short t0=f2bf(v[0]); h.x=t0; l.x=f2bf(v[0]-bf2f(t0));
    unsigned short t1=f2bf(v[1]); h.y=t1; l.y=f2bf(v[1]-bf2f(t1));
    unsigned short t2=f2bf(v[2]); h.z=t2; l.z=f2bf(v[2]-bf2f(t2));
    unsigned short t3=f2bf(v[3]); h.w=t3; l.w=f2bf(v[3]-bf2f(t3));
    *(ushort4*)(hi + i) = h;
    *(ushort4*)(lo + i) = l;
}

// ---------------- GroupNorm: partial sums ----------------
__global__ void gn_part(const float* __restrict__ x, float2* __restrict__ part){
    const int bg = blockIdx.y, blk = blockIdx.x, t = threadIdx.x;
    const float* base = x + (size_t)bg*(256*4096) + (size_t)blk*16384;
    float s = 0.f, q = 0.f;
    for (int i=0;i<16;i++){
        f32x4 v = *(const f32x4*)(base + i*1024 + t*4);
        s += v[0]+v[1]+v[2]+v[3];
        q += v[0]*v[0]+v[1]*v[1]+v[2]*v[2]+v[3]*v[3];
    }
    #pragma unroll
    for (int o=32;o>0;o>>=1){ s += __shfl_down(s, o); q += __shfl_down(q, o); }
    __shared__ float as[4], aq[4];
    if ((t&63)==0){ as[t>>6]=s; aq[t>>6]=q; }
    __syncthreads();
    if (t==0)
        part[bg*64 + blk] = make_float2(as[0]+as[1]+as[2]+as[3], aq[0]+aq[1]+aq[2]+aq[3]);
}

__global__ void gn_fin(const float2* __restrict__ part, float2* __restrict__ stats){
    const int bg = blockIdx.x, t = threadIdx.x;
    float2 p = part[bg*64 + t];
    float s = p.x, q = p.y;
    #pragma unroll
    for (int o=32;o>0;o>>=1){ s += __shfl_down(s,o); q += __shfl_down(q,o); }
    if (t==0){
        const float inv = 1.0f/(256.f*4096.f);
        float mu = s*inv;
        float var = q*inv - mu*mu;
        stats[bg] = make_float2(mu, rsqrtf(var + 1e-6f));
    }
}

// ---- GN apply + transpose + hi/lo split: x[B][C][N] -> hT[B][N][C] (bf16 hi,lo) ----
__global__ void gn_apply(const float* __restrict__ x, const float* __restrict__ gw,
                         const float* __restrict__ gb, const float2* __restrict__ stats,
                         unsigned short* __restrict__ hTh, unsigned short* __restrict__ hTl)
{
    const int b = blockIdx.z, c0 = blockIdx.y*32, n0 = blockIdx.x*32;
    const int t = threadIdx.x;
    __shared__ float tile[32][37];
    {
        const int cl = t>>3, nl = (t&7)*4;
        const int c = c0 + cl;
        const float2 st = stats[b*2 + (c>>8)];
        const float wv = gw[c], bvv = gb[c];
        const f32x4 v = *(const f32x4*)(x + ((size_t)b*C_ + c)*N_ + n0 + nl);
        #pragma unroll
        for (int i=0;i<4;i++) tile[cl][nl+i] = (v[i] - st.x)*st.y*wv + bvv;
    }
    __syncthreads();
    {
        const int nl = t>>3, cl = (t&7)*4;
        const int n = n0 + nl;
        float f0 = tile[cl+0][nl], f1 = tile[cl+1][nl], f2 = tile[cl+2][nl], f3 = tile[cl+3][nl];
        unsigned short h0=f2bf(f0), h1=f2bf(f1), h2=f2bf(f2), h3=f2bf(f3);
        ushort4 hh, ll;
        hh.x=h0; hh.y=h1; hh.z=h2; hh.w=h3;
        ll.x=f2bf(f0-bf2f(h0)); ll.y=f2bf(f1-bf2f(h1));
        ll.z=f2bf(f2-bf2f(h2)); ll.w=f2bf(f3-bf2f(h3));
        size_t o = ((size_t)b*N_ + n)*C_ + c0 + cl;
        *(ushort4*)(hTh + o) = hh;
        *(ushort4*)(hTl + o) = ll;
    }
}

// ---------------- conv GEMM: out[o,n] = sum_c W[o,c]*S[c,n] + bias[o] ----------------
// A = W [512][512] row-major (hi/lo), B = S^T [B][N][C] (hi/lo).
// PROD: 1 = hi*hi only, 3 = hi*hi + hi*lo + lo*hi.
// MODE: 0 = write outT hi/lo bf16 [B][N][C] (q,k)
//       1 = write bf16 [B][C][N] (v)
//       2 = write fp32 d_out [B][C][N] = resid + acc + bias (proj)
template<int PROD, int MODE>
__global__ __launch_bounds__(256, 2) void conv_gemm(
    const unsigned short* __restrict__ Wh, const unsigned short* __restrict__ Wl,
    const unsigned short* __restrict__ Sh, const unsigned short* __restrict__ Sl,
    const float* __restrict__ bias,
    unsigned short* __restrict__ outHi, unsigned short* __restrict__ outLo,
    float* __restrict__ outF, const float* __restrict__ resid)
{
    const int b = blockIdx.z, o0 = blockIdx.y*128, n0 = blockIdx.x*128;
    const int t = threadIdx.x, w = t>>6, l = t&63, lr = l&15, lg = l>>4;
    const int ro = (w>>1)*64, co = (w&1)*64;
    __shared__ unsigned short Ah[128][40];
    __shared__ unsigned short Al[128][40];
    __shared__ unsigned short Bh[128][40];
    __shared__ unsigned short Bl[128][40];
    f32x4 acc[4][4];
    #pragma unroll
    for (int i=0;i<4;i++)
        #pragma unroll
        for (int j=0;j<4;j++) acc[i][j] = (f32x4){0.f,0.f,0.f,0.f};

    const size_t srcB = (size_t)b*N_*C_;
    for (int ks=0; ks<16; ks++){
        const int c0 = ks*32;
        #pragma unroll
        for (int i=0;i<2;i++){
            int u = t + i*256;
            int row = u>>2, sch = (u&3)*8;
            *(bf16x8*)&Ah[row][sch] = *(const bf16x8*)(Wh + (size_t)(o0+row)*C_ + c0 + sch);
            *(bf16x8*)&Bh[row][sch] = *(const bf16x8*)(Sh + srcB + (size_t)(n0+row)*C_ + c0 + sch);
            if constexpr (PROD==3){
                *(bf16x8*)&Al[row][sch] = *(const bf16x8*)(Wl + (size_t)(o0+row)*C_ + c0 + sch);
                *(bf16x8*)&Bl[row][sch] = *(const bf16x8*)(Sl + srcB + (size_t)(n0+row)*C_ + c0 + sch);
            }
        }
        __syncthreads();
        bf16x8 af[4], bfv[4], afl[4], bfl[4];
        #pragma unroll
        for (int i=0;i<4;i++){
            af[i]  = *(const bf16x8*)&Ah[ro + i*16 + lr][lg*8];
            bfv[i] = *(const bf16x8*)&Bh[co + i*16 + lr][lg*8];
            if constexpr (PROD==3){
                afl[i] = *(const bf16x8*)&Al[ro + i*16 + lr][lg*8];
                bfl[i] = *(const bf16x8*)&Bl[co + i*16 + lr][lg*8];
            }
        }
        #pragma unroll
        for (int i=0;i<4;i++)
            #pragma unroll
            for (int j=0;j<4;j++){
                acc[i][j] = mfma16(af[i], bfv[j], acc[i][j]);
                if constexpr (PROD==3){
                    acc[i][j] = mfma16(af[i],  bfl[j], acc[i][j]);
                    acc[i][j] = mfma16(afl[i], bfv[j], acc[i][j]);
                }
            }
        __syncthreads();
    }
    #pragma unroll
    for (int i=0;i<4;i++){
        const int ob = o0 + ro + i*16 + lg*4;
        #pragma unroll
        for (int j=0;j<4;j++){
            const int n = n0 + co + j*16 + lr;
            f32x4 v = acc[i][j];
            if constexpr (MODE==0){
                float v0 = v[0] + bias[ob+0]; unsigned short h0 = f2bf(v0);
                float v1 = v[1] + bias[ob+1]; unsigned short h1 = f2bf(v1);
                float v2 = v[2] + bias[ob+2]; unsigned short h2 = f2bf(v2);
                float v3 = v[3] + bias[ob+3]; unsigned short h3 = f2bf(v3);
                ushort4 hh, ll;
                hh.x=h0; hh.y=h1; hh.z=h2; hh.w=h3;
                ll.x=f2bf(v0-bf2f(h0)); ll.y=f2bf(v1-bf2f(h1));
                ll.z=f2bf(v2-bf2f(h2)); ll.w=f2bf(v3-bf2f(h3));
                *(ushort4*)(outHi + srcB + (size_t)n*C_ + ob) = hh;
                *(ushort4*)(outLo + srcB + (size_t)n*C_ + ob) = ll;
            } else if constexpr (MODE==1){
                #pragma unroll
                for (int r=0;r<4;r++)
                    outHi[((size_t)b*C_ + ob + r)*N_ + n] = f2bf(v[r] + bias[ob+r]);
            } else {
                #pragma unroll
                for (int r=0;r<4;r++){
                    size_t idx = ((size_t)b*C_ + ob + r)*N_ + n;
                    outF[idx] = resid[idx] + v[r] + bias[ob+r];
                }
            }
        }
    }
}

// ---------------- flash attention ----------------
// S[n,m] = sum_c q[n,c]k[m,c] * 22.627, online softmax over m, O[n,c] = sum_m P[n,m] v[c,m].
// qT/kT: [B][N][C] bf16 hi/lo.  v: [B][C][N] bf16.  out aoT: [B][N][C] bf16.
__global__ __launch_bounds__(512, 2) void attn_flash(
    const unsigned short* __restrict__ qTh, const unsigned short* __restrict__ qTl,
    const unsigned short* __restrict__ kTh, const unsigned short* __restrict__ kTl,
    const unsigned short* __restrict__ vB,  unsigned short* __restrict__ aoT)
{
    const int b = blockIdx.y, n0 = blockIdx.x*64;
    const int t = threadIdx.x, w = t>>6, l = t&63, lr = l&15, lg = l>>4;
    const int fm = w>>1, fn = w&1, cw = w*64;
    __shared__ unsigned short kh[32*512];   // XOR-swizzled [m][c] tile
    __shared__ unsigned short kl[32*512];
    __shared__ float Sb[64][40];
    __shared__ unsigned short Pb[64][40];
    __shared__ float rowM[64], rowS[64], rowF[64];

    // preload this wave's q fragments (rows fm*16..+15, full C) hi+lo
    bf16x8 qh[16], ql[16];
    {
        const size_t qr = ((size_t)b*N_ + n0 + fm*16 + lr)*C_;
        #pragma unroll
        for (int kc=0; kc<16; kc++){
            qh[kc] = *(const bf16x8*)(qTh + qr + kc*32 + lg*8);
            ql[kc] = *(const bf16x8*)(qTl + qr + kc*32 + lg*8);
        }
    }
    f32x4 acc[4][4];
    #pragma unroll
    for (int i=0;i<4;i++)
        #pragma unroll
        for (int j=0;j<4;j++) acc[i][j] = (f32x4){0.f,0.f,0.f,0.f};
    if (t < 64){ rowM[t] = -INFINITY; rowS[t] = 0.f; }

    // stage k tile mt=0
    #pragma unroll
    for (int i=0;i<4;i++){
        int u = t + i*512;
        int row = u>>6, c16 = u&63;
        size_t g = ((size_t)b*N_ + row)*C_ + c16*8;
        int o = row*1024 + ((c16*16) ^ ((row&7)<<4));
        *(bf16x8*)((char*)kh + o) = *(const bf16x8*)(kTh + g);
        *(bf16x8*)((char*)kl + o) = *(const bf16x8*)(kTl + g);
    }
    __syncthreads();

    for (int mt=0; mt<128; mt++){
        const int m0 = mt*32;
        // S fragment for this wave (rows fm, cols fn), split-precision: 3 indep chains
        f32x4 s0 = (f32x4){0.f,0.f,0.f,0.f}, s1 = s0, s2 = s0;
        {
            const int krow = fn*16 + lr;
            const int swz = (krow&7)<<4;
            #pragma unroll
            for (int kc=0;kc<16;kc++){
                const int o = krow*1024 + ((kc*64 + lg*16) ^ swz);
                bf16x8 kf  = *(const bf16x8*)((const char*)kh + o);
                bf16x8 kfl = *(const bf16x8*)((const char*)kl + o);
                s0 = mfma16(qh[kc], kf,  s0);
                s1 = mfma16(qh[kc], kfl, s1);
                s2 = mfma16(ql[kc], kf,  s2);
            }
        }
        #pragma unroll
        for (int r=0;r<4;r++)
            Sb[fm*16 + lg*4 + r][fn*16 + lr] = (s0[r]+s1[r]+s2[r])*22.62741699796952f;
        __syncthreads();
        // online softmax: 8 threads per row
        {
            const int row = t>>3, j = t&7;
            float a0 = Sb[row][j*4+0], a1 = Sb[row][j*4+1];
            float a2 = Sb[row][j*4+2], a3 = Sb[row][j*4+3];
            float mx = fmaxf(fmaxf(a0,a1), fmaxf(a2,a3));
            mx = fmaxf(mx, __shfl_xor(mx, 1, 8));
            mx = fmaxf(mx, __shfl_xor(mx, 2, 8));
            mx = fmaxf(mx, __shfl_xor(mx, 4, 8));
            const float mprev = rowM[row];
            const float mnew = fmaxf(mprev, mx);
            float p0 = __expf(a0 - mnew), p1 = __expf(a1 - mnew);
            float p2 = __expf(a2 - mnew), p3 = __expf(a3 - mnew);
            float ps = p0+p1+p2+p3;
            ps += __shfl_xor(ps, 1, 8);
            ps += __shfl_xor(ps, 2, 8);
            ps += __shfl_xor(ps, 4, 8);
            ushort4 pk; pk.x=f2bf(p0); pk.y=f2bf(p1); pk.z=f2bf(p2); pk.w=f2bf(p3);
            *(ushort4*)&Pb[row][j*4] = pk;
            if (j==0){
                float f = __expf(mprev - mnew);
                rowF[row] = f;
                rowS[row] = rowS[row]*f + ps;
                rowM[row] = mnew;
            }
        }
        __syncthreads();
        // rescale + PV; prefetch-stage next k tile
        #pragma unroll
        for (int am=0;am<4;am++)
            #pragma unroll
            for (int r=0;r<4;r++){
                const float f = rowF[am*16 + lg*4 + r];
                #pragma unroll
                for (int ac=0;ac<4;ac++) acc[am][ac][r] *= f;
            }
        bf16x8 pa[4];
        #pragma unroll
        for (int am=0;am<4;am++) pa[am] = *(const bf16x8*)&Pb[am*16 + lr][lg*8];
        #pragma unroll
        for (int ac=0;ac<4;ac++){
            const size_t vi = ((size_t)b*C_ + cw + ac*16 + lr)*N_ + m0 + lg*8;
            bf16x8 vf = *(const bf16x8*)(vB + vi);
            #pragma unroll
            for (int am=0;am<4;am++) acc[am][ac] = mfma16(pa[am], vf, acc[am][ac]);
        }
        if (mt < 127){
            const int m1 = m0 + 32;
            #pragma unroll
            for (int i=0;i<4;i++){
                int u = t + i*512;
                int row = u>>6, c16 = u&63;
                size_t g = ((size_t)b*N_ + m1 + row)*C_ + c16*8;
                int o = row*1024 + ((c16*16) ^ ((row&7)<<4));
                *(bf16x8*)((char*)kh + o) = *(const bf16x8*)(kTh + g);
                *(bf16x8*)((char*)kl + o) = *(const bf16x8*)(kTl + g);
            }
        }
        __syncthreads();
    }
    // normalize + write out aoT[B][N][C]
    #pragma unroll
    for (int am=0;am<4;am++)
        #pragma unroll
        for (int r=0;r<4;r++){
            const int n = am*16 + lg*4 + r;
            const float inv = 1.0f / rowS[n];
            #pragma unroll
            for (int ac=0;ac<4;ac++)
                aoT[((size_t)b*N_ + n0 + n)*C_ + cw + ac*16 + lr] = f2bf(acc[am][ac][r]*inv);
        }
}

extern "C" void kernel_launch(void* const* d_in, const int* in_sizes, int n_in,
                              void* d_out, int out_size, void* d_ws, size_t ws_size,
                              hipStream_t stream)
{
    const float* x   = (const float*)d_in[0];
    const float* gnw = (const float*)d_in[1];
    const float* gnb = (const float*)d_in[2];
    const float* wq  = (const float*)d_in[3];
    const float* bq  = (const float*)d_in[4];
    const float* wk  = (const float*)d_in[5];
    const float* bk  = (const float*)d_in[6];
    const float* wv  = (const float*)d_in[7];
    const float* bv  = (const float*)d_in[8];
    const float* wp  = (const float*)d_in[9];
    const float* bp  = (const float*)d_in[10];
    float* out = (float*)d_out;

    // workspace layout (~139 MB)
    char* ws = (char*)d_ws;
    size_t off = 0;
    auto alloc = [&](size_t bytes)->char*{
        char* p = ws + off; off += (bytes + 255) & ~(size_t)255; return p;
    };
    const size_t WB = (size_t)C_*C_*2;     // one bf16 weight buffer
    const size_t TB = (size_t)B_*N_*C_*2;  // one bf16 tensor buffer
    unsigned short* wqh = (unsigned short*)alloc(WB);
    unsigned short* wql = (unsigned short*)alloc(WB);
    unsigned short* wkh = (unsigned short*)alloc(WB);
    unsigned short* wkl = (unsigned short*)alloc(WB);
    unsigned short* wvh = (unsigned short*)alloc(WB);
    unsigned short* wvl = (unsigned short*)alloc(WB);
    unsigned short* wph = (unsigned short*)alloc(WB);
    unsigned short* wpl = (unsigned short*)alloc(WB);
    unsigned short* hTh = (unsigned short*)alloc(TB);
    unsigned short* hTl = (unsigned short*)alloc(TB);
    unsigned short* qTh = (unsigned short*)alloc(TB);
    unsigned short* qTl = (unsigned short*)alloc(TB);
    unsigned short* kTh = (unsigned short*)alloc(TB);
    unsigned short* kTl = (unsigned short*)alloc(TB);
    unsigned short* vb  = (unsigned short*)alloc(TB);
    unsigned short* ao  = (unsigned short*)alloc(TB);
    float2* part  = (float2*)alloc(8*64*sizeof(float2));
    float2* stats = (float2*)alloc(8*sizeof(float2));

    split_w<<<256, 256, 0, stream>>>(wq, wqh, wql);
    split_w<<<256, 256, 0, stream>>>(wk, wkh, wkl);
    split_w<<<256, 256, 0, stream>>>(wv, wvh, wvl);
    split_w<<<256, 256, 0, stream>>>(wp, wph, wpl);
    gn_part<<<dim3(64, 8), 256, 0, stream>>>(x, part);
    gn_fin<<<8, 64, 0, stream>>>(part, stats);
    gn_apply<<<dim3(128, 16, B_), 256, 0, stream>>>(x, gnw, gnb, stats, hTh, hTl);
    conv_gemm<3,0><<<dim3(32,4,B_), 256, 0, stream>>>(wqh,wql,hTh,hTl,bq, qTh,qTl,nullptr,nullptr);
    conv_gemm<3,0><<<dim3(32,4,B_), 256, 0, stream>>>(wkh,wkl,hTh,hTl,bk, kTh,kTl,nullptr,nullptr);
    conv_gemm<1,1><<<dim3(32,4,B_), 256, 0, stream>>>(wvh,wvl,hTh,hTl,bv, vb,nullptr,nullptr,nullptr);
    attn_flash<<<dim3(64, B_), 512, 0, stream>>>(qTh,qTl,kTh,kTl,vb,ao);
    conv_gemm<1,2><<<dim3(32,4,B_), 256, 0, stream>>>(wph,wpl,ao,nullptr,bp, nullptr,nullptr,out,x);
}